// Round 2
// baseline (2245.315 us; speedup 1.0000x reference)
//
#include <hip/hip_runtime.h>
#include <hip/hip_bf16.h>

#define N_NODES 100000
#define N_EDGES 3200000
#define IN_F    512
#define NH      64
#define NC      16
#define K_HOPS  10

// ---------------- Fused encoder: z = relu(X@W1+b1)@W2 + b2 ----------------
// 64-row tile per block, 256 threads. Writes z (f32) and hidden = temp[0]*z.
__global__ __launch_bounds__(256) void encoder_kernel(
    const float* __restrict__ X, const float* __restrict__ W1,
    const float* __restrict__ b1, const float* __restrict__ W2,
    const float* __restrict__ b2, const float* __restrict__ temp,
    float* __restrict__ z, float* __restrict__ hidden)
{
    __shared__ float Xs[64][33];    // +1 pad
    __shared__ float W1s[32][64];
    __shared__ float hs[64][65];    // +1 pad
    __shared__ float W2s[64][16];
    __shared__ float b1s[64];
    __shared__ float b2s[16];

    const int t = threadIdx.x;
    const int blockRow = blockIdx.x * 64;

    if (t < 64) b1s[t] = b1[t];
    if (t < 16) b2s[t] = b2[t];
    for (int l = t; l < NH * NC; l += 256) W2s[l / NC][l % NC] = W2[l];

    const int tx = t % 16;          // col group (×4 -> 64 cols)
    const int ty = t / 16;          // row group (×4 -> 64 rows)

    float acc[4][4] = {{0.f}};

    for (int kc = 0; kc < IN_F; kc += 32) {
        __syncthreads();
        // stage X tile [64][32]
        #pragma unroll
        for (int s = 0; s < 8; ++s) {
            int l = t + 256 * s;
            int r = l >> 5, kk = l & 31;
            int gr = blockRow + r;
            Xs[r][kk] = (gr < N_NODES) ? X[(size_t)gr * IN_F + kc + kk] : 0.f;
        }
        // stage W1 tile [32][64]
        #pragma unroll
        for (int s = 0; s < 8; ++s) {
            int l = t + 256 * s;
            int kr = l >> 6, c = l & 63;
            W1s[kr][c] = W1[(size_t)(kc + kr) * NH + c];
        }
        __syncthreads();
        #pragma unroll
        for (int k = 0; k < 32; ++k) {
            float xv[4], wv[4];
            #pragma unroll
            for (int i = 0; i < 4; ++i) xv[i] = Xs[ty + 16 * i][k];
            #pragma unroll
            for (int j = 0; j < 4; ++j) wv[j] = W1s[k][tx + 16 * j];
            #pragma unroll
            for (int i = 0; i < 4; ++i)
                #pragma unroll
                for (int j = 0; j < 4; ++j)
                    acc[i][j] += xv[i] * wv[j];
        }
    }
    __syncthreads();
    // relu(h + b1) -> LDS
    #pragma unroll
    for (int i = 0; i < 4; ++i)
        #pragma unroll
        for (int j = 0; j < 4; ++j) {
            float v = acc[i][j] + b1s[tx + 16 * j];
            hs[ty + 16 * i][tx + 16 * j] = v > 0.f ? v : 0.f;
        }
    __syncthreads();

    // GEMM2: z[64][16] = hs[64][64] @ W2s[64][16]
    const int c2 = t % 16;
    const int rr = t / 16;
    float acc2[4] = {0.f, 0.f, 0.f, 0.f};
    #pragma unroll
    for (int k = 0; k < NH; ++k) {
        float w2 = W2s[k][c2];
        #pragma unroll
        for (int m = 0; m < 4; ++m) acc2[m] += hs[rr + 16 * m][k] * w2;
    }
    const float t0 = temp[0];
    #pragma unroll
    for (int m = 0; m < 4; ++m) {
        int gr = blockRow + rr + 16 * m;
        if (gr < N_NODES) {
            float zv = acc2[m] + b2s[c2];
            z[(size_t)gr * NC + c2] = zv;
            hidden[(size_t)gr * NC + c2] = t0 * zv;
        }
    }
}

// ---------------- SpMM scatter: out[dst] += w * in[src] ----------------
// 16 lanes per edge, one float column each.
__global__ __launch_bounds__(256) void spmm_kernel(
    const int* __restrict__ src, const int* __restrict__ dst,
    const float* __restrict__ w, const float* __restrict__ in,
    float* __restrict__ out)
{
    int tid = blockIdx.x * 256 + threadIdx.x;
    int e = tid >> 4;
    int c = tid & 15;
    if (e >= N_EDGES) return;
    int s = src[e];
    int d = dst[e];
    float val = w[e] * in[(size_t)s * NC + c];
    atomicAdd(&out[(size_t)d * NC + c], val);
}

// ---------------- hidden += gamma * zk (f32, into d_out) ----------------
__global__ __launch_bounds__(256) void axpy_kernel(
    float* __restrict__ hidden, const float* __restrict__ zk,
    const float* __restrict__ temp, int k)
{
    int i = blockIdx.x * 256 + threadIdx.x;
    if (i < N_NODES * NC) hidden[i] += temp[k] * zk[i];
}

extern "C" void kernel_launch(void* const* d_in, const int* in_sizes, int n_in,
                              void* d_out, int out_size, void* d_ws, size_t ws_size,
                              hipStream_t stream)
{
    const float* feature = (const float*)d_in[0];
    const float* W1      = (const float*)d_in[1];
    const float* b1      = (const float*)d_in[2];
    const float* W2      = (const float*)d_in[3];
    const float* b2      = (const float*)d_in[4];
    const int*   edges   = (const int*)d_in[5];   // [2][N_EDGES] flat, int32
    const float* norm_A  = (const float*)d_in[6];
    const float* temp    = (const float*)d_in[7];

    const int* src = edges;
    const int* dst = edges + N_EDGES;

    const size_t stateBytes = (size_t)N_NODES * NC * sizeof(float); // 6.4 MB
    float* zkA    = (float*)d_ws;
    float* zkB    = (float*)((char*)d_ws + stateBytes);
    float* hidden = (float*)d_out;   // f32 accumulator lives in d_out

    // encoder: z -> zkA, hidden = temp[0]*z
    {
        dim3 grid((N_NODES + 63) / 64);
        encoder_kernel<<<grid, 256, 0, stream>>>(feature, W1, b1, W2, b2, temp,
                                                 zkA, hidden);
    }

    const int spmmGrid = (N_EDGES * NC + 255) / 256;       // 200000
    const int vecGrid  = (N_NODES * NC + 255) / 256;       // 6250

    float* cur = zkA;
    float* nxt = zkB;
    for (int k = 1; k <= K_HOPS; ++k) {
        hipMemsetAsync(nxt, 0, stateBytes, stream);
        spmm_kernel<<<spmmGrid, 256, 0, stream>>>(src, dst, norm_A, cur, nxt);
        axpy_kernel<<<vecGrid, 256, 0, stream>>>(hidden, nxt, temp, k);
        float* t2 = cur; cur = nxt; nxt = t2;
    }
}

// Round 3
// 1051.807 us; speedup vs baseline: 2.1347x; 2.1347x over previous
//
#include <hip/hip_runtime.h>
#include <hip/hip_bf16.h>

#define NN 100000
#define NE 3200000
#define IN_F 512
#define NH 64
#define NC 16
#define K_HOPS 10

typedef short bf16x8 __attribute__((ext_vector_type(8)));
typedef float f32x4 __attribute__((ext_vector_type(4)));

__device__ __forceinline__ short f2bf_s(float x) {
    __hip_bfloat16 b = __float2bfloat16(x);
    return *reinterpret_cast<short*>(&b);
}
__device__ __forceinline__ float bf2f_s(short s) {
    __hip_bfloat16 b = *reinterpret_cast<__hip_bfloat16*>(&s);
    return __bfloat162float(b);
}

// split 8 f32 (two f32x4) into hi/lo bf16x8 fragments
__device__ __forceinline__ void split8(const f32x4 a, const f32x4 b,
                                       bf16x8& hi, bf16x8& lo) {
    float x[8] = {a[0], a[1], a[2], a[3], b[0], b[1], b[2], b[3]};
#pragma unroll
    for (int j = 0; j < 8; ++j) {
        short h = f2bf_s(x[j]);
        hi[j] = h;
        lo[j] = f2bf_s(x[j] - bf2f_s(h));
    }
}

__device__ __forceinline__ f32x4 mfma3(bf16x8 ah, bf16x8 al, bf16x8 bh,
                                       bf16x8 bl, f32x4 c) {
    c = __builtin_amdgcn_mfma_f32_16x16x32_bf16(ah, bh, c, 0, 0, 0);
    c = __builtin_amdgcn_mfma_f32_16x16x32_bf16(ah, bl, c, 0, 0, 0);
    c = __builtin_amdgcn_mfma_f32_16x16x32_bf16(al, bh, c, 0, 0, 0);
    return c;
}

// ---------- prep: W1 -> W1T hi/lo bf16 [64][512], W2 -> W2T hi/lo [16][64] ----------
__global__ __launch_bounds__(256) void conv_w_kernel(
    const float* __restrict__ W1, const float* __restrict__ W2,
    short* __restrict__ w1h, short* __restrict__ w1l,
    short* __restrict__ w2h, short* __restrict__ w2l)
{
    int i = blockIdx.x * 256 + threadIdx.x;
    if (i < IN_F * NH) {
        int k = i >> 6, n = i & 63;          // W1[k][n]
        float v = W1[i];
        short h = f2bf_s(v);
        w1h[n * IN_F + k] = h;
        w1l[n * IN_F + k] = f2bf_s(v - bf2f_s(h));
    } else if (i < IN_F * NH + NH * NC) {
        int j = i - IN_F * NH;
        int k = j >> 4, c = j & 15;          // W2[k][c]
        float v = W2[j];
        short h = f2bf_s(v);
        w2h[c * NH + k] = h;
        w2l[c * NH + k] = f2bf_s(v - bf2f_s(h));
    }
}

// ---------- encoder: z = relu(X@W1+b1)@W2+b2 ; hid = temp[0]*z ----------
// 256 thr = 4 waves; wave owns 32 rows (2 m-tiles of 16), full 64 cols of h.
// GEMM1 straight from global (X f32 -> in-reg hi/lo frags; W1T bf16 L2-hit).
// h -> LDS f32 (wave-private rows), GEMM2 via MFMA again.
__global__ __launch_bounds__(256) void encoder_mfma(
    const float* __restrict__ X,
    const short* __restrict__ w1h, const short* __restrict__ w1l,
    const short* __restrict__ w2h, const short* __restrict__ w2l,
    const float* __restrict__ b1, const float* __restrict__ b2,
    const float* __restrict__ temp,
    float* __restrict__ z, float* __restrict__ hid)
{
    __shared__ float hs[128 * 68];           // [128 rows][68 pad] f32
    const int t = threadIdx.x;
    const int wave = t >> 6, lane = t & 63;
    const int lm = lane & 15, kg = lane >> 4;
    const int wrow = blockIdx.x * 128 + wave * 32;

    // clamped row pointers (OOB rows compute garbage, never stored)
    int r0 = wrow + lm;       if (r0 > NN - 1) r0 = NN - 1;
    int r1 = wrow + 16 + lm;  if (r1 > NN - 1) r1 = NN - 1;
    const float* xp0 = X + (size_t)r0 * IN_F + kg * 8;
    const float* xp1 = X + (size_t)r1 * IN_F + kg * 8;
    const short* bhp = w1h + lm * IN_F + kg * 8;   // + nt*16*IN_F
    const short* blp = w1l + lm * IN_F + kg * 8;

    f32x4 acc[2][4];
#pragma unroll
    for (int m = 0; m < 2; ++m)
#pragma unroll
        for (int n = 0; n < 4; ++n) acc[m][n] = (f32x4){0.f, 0.f, 0.f, 0.f};

    for (int kb = 0; kb < IN_F; kb += 32) {
        bf16x8 ah0, al0, ah1, al1;
        {
            const f32x4* p0 = reinterpret_cast<const f32x4*>(xp0 + kb);
            split8(p0[0], p0[1], ah0, al0);
            const f32x4* p1 = reinterpret_cast<const f32x4*>(xp1 + kb);
            split8(p1[0], p1[1], ah1, al1);
        }
#pragma unroll
        for (int nt = 0; nt < 4; ++nt) {
            bf16x8 bh = *reinterpret_cast<const bf16x8*>(bhp + nt * 16 * IN_F + kb);
            bf16x8 bl = *reinterpret_cast<const bf16x8*>(blp + nt * 16 * IN_F + kb);
            acc[0][nt] = mfma3(ah0, al0, bh, bl, acc[0][nt]);
            acc[1][nt] = mfma3(ah1, al1, bh, bl, acc[1][nt]);
        }
    }

    // bias + relu -> LDS (D layout: row = kg*4+reg, col = lm within tile)
    float b1v[4];
#pragma unroll
    for (int nt = 0; nt < 4; ++nt) b1v[nt] = b1[nt * 16 + lm];
#pragma unroll
    for (int m = 0; m < 2; ++m)
#pragma unroll
        for (int nt = 0; nt < 4; ++nt)
#pragma unroll
            for (int r = 0; r < 4; ++r) {
                float v = acc[m][nt][r] + b1v[nt];
                v = v > 0.f ? v : 0.f;
                hs[(wave * 32 + m * 16 + kg * 4 + r) * 68 + nt * 16 + lm] = v;
            }
    // wave-private rows: no __syncthreads needed (compiler orders ds ops)

    // GEMM2: [32 x 64] @ [64 x 16]
    f32x4 acc2[2];
    acc2[0] = (f32x4){0.f, 0.f, 0.f, 0.f};
    acc2[1] = (f32x4){0.f, 0.f, 0.f, 0.f};
#pragma unroll
    for (int kb = 0; kb < NH; kb += 32) {
        bf16x8 bh = *reinterpret_cast<const bf16x8*>(w2h + lm * NH + kb + kg * 8);
        bf16x8 bl = *reinterpret_cast<const bf16x8*>(w2l + lm * NH + kb + kg * 8);
#pragma unroll
        for (int m = 0; m < 2; ++m) {
            const f32x4* hp = reinterpret_cast<const f32x4*>(
                &hs[(wave * 32 + m * 16 + lm) * 68 + kb + kg * 8]);
            bf16x8 ah, al;
            split8(hp[0], hp[1], ah, al);
            acc2[m] = mfma3(ah, al, bh, bl, acc2[m]);
        }
    }

    const float b2v = b2[lm];
    const float t0 = temp[0];
#pragma unroll
    for (int m = 0; m < 2; ++m)
#pragma unroll
        for (int r = 0; r < 4; ++r) {
            int node = wrow + m * 16 + kg * 4 + r;
            if (node < NN) {
                float zv = acc2[m][r] + b2v;
                z[(size_t)node * NC + lm] = zv;
                hid[(size_t)node * NC + lm] = t0 * zv;
            }
        }
}

// ---------- CSR build ----------
__global__ __launch_bounds__(256) void hist_kernel(const int* __restrict__ dst,
                                                   int* __restrict__ cnt)
{
    int e = blockIdx.x * 256 + threadIdx.x;
    if (e < NE) atomicAdd(&cnt[dst[e]], 1);
}

__global__ __launch_bounds__(256) void scan1_kernel(const int* __restrict__ cnt,
                                                    int* __restrict__ excl,
                                                    int* __restrict__ bsum)
{
    __shared__ int s[256];
    int tid = threadIdx.x;
    int d = blockIdx.x * 256 + tid;
    int v = (d < NN) ? cnt[d] : 0;
    s[tid] = v;
    __syncthreads();
    for (int off = 1; off < 256; off <<= 1) {
        int u = (tid >= off) ? s[tid - off] : 0;
        __syncthreads();
        s[tid] += u;
        __syncthreads();
    }
    if (d < NN) excl[d] = s[tid] - v;
    if (tid == 255) bsum[blockIdx.x] = s[255];
}

#define NBLK 391
__global__ __launch_bounds__(512) void scan2_kernel(const int* __restrict__ bsum,
                                                    int* __restrict__ boff)
{
    __shared__ int s[512];
    int tid = threadIdx.x;
    int v = (tid < NBLK) ? bsum[tid] : 0;
    s[tid] = v;
    __syncthreads();
    for (int off = 1; off < 512; off <<= 1) {
        int u = (tid >= off) ? s[tid - off] : 0;
        __syncthreads();
        s[tid] += u;
        __syncthreads();
    }
    if (tid < NBLK) boff[tid] = s[tid] - v;
}

__global__ __launch_bounds__(256) void scan3_kernel(const int* __restrict__ excl,
                                                    const int* __restrict__ boff,
                                                    int* __restrict__ row_start,
                                                    int* __restrict__ cursor)
{
    int d = blockIdx.x * 256 + threadIdx.x;
    if (d < NN) {
        int rs = excl[d] + boff[blockIdx.x];
        row_start[d] = rs;
        cursor[d] = rs;
    }
}

__global__ __launch_bounds__(256) void fill_kernel(
    const int* __restrict__ src, const int* __restrict__ dst,
    const float* __restrict__ w, int* __restrict__ cursor,
    int* __restrict__ srcs, float* __restrict__ wq)
{
    int e = blockIdx.x * 256 + threadIdx.x;
    if (e < NE) {
        int d = dst[e];
        int p = atomicAdd(&cursor[d], 1);
        srcs[p] = src[e];
        wq[p] = w[e];
    }
}

// ---------- hop: out[d] = sum_e w*in[src]; hid[d] += temp[k]*out[d] ----------
__global__ __launch_bounds__(256) void hop_kernel(
    const int* __restrict__ row_start, const int* __restrict__ srcs,
    const float* __restrict__ wq, const float* __restrict__ in,
    float* __restrict__ out, float* __restrict__ hid,
    const float* __restrict__ temp, int k)
{
    int tid = blockIdx.x * 256 + threadIdx.x;
    int d = tid >> 4, c = tid & 15;
    if (d >= NN) return;
    int e = row_start[d];
    const int e1 = (d + 1 < NN) ? row_start[d + 1] : NE;
    float a0 = 0.f, a1 = 0.f;
    for (; e + 1 < e1; e += 2) {
        int s0 = srcs[e], s1 = srcs[e + 1];
        float w0 = wq[e], w1 = wq[e + 1];
        a0 += w0 * in[(size_t)s0 * NC + c];
        a1 += w1 * in[(size_t)s1 * NC + c];
    }
    if (e < e1) a0 += wq[e] * in[(size_t)srcs[e] * NC + c];
    float r = a0 + a1;
    out[tid] = r;
    hid[tid] += temp[k] * r;
}

// ---------- fallback (small ws): atomic scatter + axpy ----------
__global__ __launch_bounds__(256) void spmm_atomic_kernel(
    const int* __restrict__ src, const int* __restrict__ dst,
    const float* __restrict__ w, const float* __restrict__ in,
    float* __restrict__ out)
{
    int tid = blockIdx.x * 256 + threadIdx.x;
    int e = tid >> 4, c = tid & 15;
    if (e >= NE) return;
    float val = w[e] * in[(size_t)src[e] * NC + c];
    atomicAdd(&out[(size_t)dst[e] * NC + c], val);
}
__global__ __launch_bounds__(256) void axpy_kernel(
    float* __restrict__ hid, const float* __restrict__ zk,
    const float* __restrict__ temp, int k)
{
    int i = blockIdx.x * 256 + threadIdx.x;
    if (i < NN * NC) hid[i] += temp[k] * zk[i];
}

extern "C" void kernel_launch(void* const* d_in, const int* in_sizes, int n_in,
                              void* d_out, int out_size, void* d_ws, size_t ws_size,
                              hipStream_t stream)
{
    const float* feature = (const float*)d_in[0];
    const float* W1      = (const float*)d_in[1];
    const float* b1      = (const float*)d_in[2];
    const float* W2      = (const float*)d_in[3];
    const float* b2      = (const float*)d_in[4];
    const int*   edges   = (const int*)d_in[5];
    const float* norm_A  = (const float*)d_in[6];
    const float* temp    = (const float*)d_in[7];
    const int* src = edges;
    const int* dst = edges + NE;
    float* hid = (float*)d_out;

    // workspace carve
    char* p = (char*)d_ws;
    size_t off = 0;
    auto carve = [&](size_t bytes) {
        void* r = p + off;
        off += (bytes + 255) & ~(size_t)255;
        return r;
    };
    float* zkA  = (float*)carve((size_t)NN * NC * 4);
    float* zkB  = (float*)carve((size_t)NN * NC * 4);
    short* w1h  = (short*)carve((size_t)IN_F * NH * 2);
    short* w1l  = (short*)carve((size_t)IN_F * NH * 2);
    short* w2h  = (short*)carve((size_t)NH * NC * 2);
    short* w2l  = (short*)carve((size_t)NH * NC * 2);
    size_t baseNeed = off;
    int*   cnt      = (int*)carve((size_t)NN * 4);
    int*   excl     = (int*)carve((size_t)NN * 4);
    int*   rowst    = (int*)carve((size_t)NN * 4);
    int*   cursor   = (int*)carve((size_t)NN * 4);
    int*   bsum     = (int*)carve(2048);
    int*   boff     = (int*)carve(2048);
    int*   srcs     = (int*)carve((size_t)NE * 4);
    float* wq       = (float*)carve((size_t)NE * 4);
    const bool useCSR = (off <= ws_size);

    // prep weights + encoder
    conv_w_kernel<<<(IN_F * NH + NH * NC + 255) / 256, 256, 0, stream>>>(
        W1, W2, w1h, w1l, w2h, w2l);
    encoder_mfma<<<(NN + 127) / 128, 256, 0, stream>>>(
        feature, w1h, w1l, w2h, w2l, b1, b2, temp, zkA, hid);

    const int vecGrid  = (NN * NC + 255) / 256;      // 6250
    const int edgeGrid = (NE + 255) / 256;           // 12500

    if (useCSR) {
        hipMemsetAsync(cnt, 0, (size_t)NN * 4, stream);
        hist_kernel<<<edgeGrid, 256, 0, stream>>>(dst, cnt);
        scan1_kernel<<<NBLK, 256, 0, stream>>>(cnt, excl, bsum);
        scan2_kernel<<<1, 512, 0, stream>>>(bsum, boff);
        scan3_kernel<<<NBLK, 256, 0, stream>>>(excl, boff, rowst, cursor);
        fill_kernel<<<edgeGrid, 256, 0, stream>>>(src, dst, norm_A, cursor, srcs, wq);

        float* cur = zkA;
        float* nxt = zkB;
        for (int k = 1; k <= K_HOPS; ++k) {
            hop_kernel<<<vecGrid, 256, 0, stream>>>(rowst, srcs, wq, cur, nxt,
                                                    hid, temp, k);
            float* t2 = cur; cur = nxt; nxt = t2;
        }
    } else {
        (void)baseNeed;
        const int spmmGrid = (NE * NC + 255) / 256;
        float* cur = zkA;
        float* nxt = zkB;
        for (int k = 1; k <= K_HOPS; ++k) {
            hipMemsetAsync(nxt, 0, (size_t)NN * NC * 4, stream);
            spmm_atomic_kernel<<<spmmGrid, 256, 0, stream>>>(src, dst, norm_A, cur, nxt);
            axpy_kernel<<<vecGrid, 256, 0, stream>>>(hid, nxt, temp, k);
            float* t2 = cur; cur = nxt; nxt = t2;
        }
    }
}